// Round 1
// 1602.336 us; speedup vs baseline: 1.2739x; 1.2739x over previous
//
#include <hip/hip_runtime.h>
#include <math.h>

// LstmCellRudder persistent MFMA kernel, round 8.
// B=256, T=512, D=160 (obs128+act32), H=512, gates 4H=2048, K=672.
// Grid 256 blocks x 256 threads (4 waves, 1 block/CU). 16 bgrps x 16 blocks,
// XCD-pure runtime negotiation (verified R4-R6).
// NEW vs R7 (critical-path restructure; ring latency was ~80% of step time):
//  - h published DIRECTLY in consumer fragment layout: j-local = w*8+q*2+ti
//    remap means each lane's 2 epilogue halves form one fragment dword ->
//    per-wave 1x4B-store publish, per-wave flags (64/bgrp), NO hbuf, NO S2.
//  - consumer h-stage = verbatim 16KB copy (coalesced, b128 LDS, linear).
//  - x-part MFMA moved after P, overlapping the h-stage load latency;
//    x region double-buffered in LDS (2x5KB) so no extra barrier needed.
//  - y-dot moved after flag store (runs in next poll's shadow); partials
//    consumed next iteration (out index shifted by 1; tail writes out[510]).
//  - split-K h-MFMA (4 acc chains) -> issue-bound, not latency-bound.
//  - v_rcp_f32 in sigmoid/tanh instead of precise f32 divides.
// Barriers per step: 3 -> 2 (P, S0).

namespace {
constexpr int kT = 512, kH = 512;

typedef _Float16 v8h __attribute__((ext_vector_type(8)));
typedef float v4f __attribute__((ext_vector_type(4)));
typedef unsigned long long ull;
typedef ull v2u __attribute__((ext_vector_type(2)));

__device__ __forceinline__ ull ld64sc(const ull* p, bool sys) {
    return sys ? __hip_atomic_load(p, __ATOMIC_RELAXED, __HIP_MEMORY_SCOPE_SYSTEM)
               : __hip_atomic_load(p, __ATOMIC_RELAXED, __HIP_MEMORY_SCOPE_AGENT);
}
__device__ __forceinline__ unsigned ld32sc(const unsigned* p, bool sys) {
    return sys ? __hip_atomic_load(p, __ATOMIC_RELAXED, __HIP_MEMORY_SCOPE_SYSTEM)
               : __hip_atomic_load(p, __ATOMIC_RELAXED, __HIP_MEMORY_SCOPE_AGENT);
}
__device__ __forceinline__ void st32sc(unsigned* p, unsigned v, bool sys) {
    if (sys) __hip_atomic_store(p, v, __ATOMIC_RELAXED, __HIP_MEMORY_SCOPE_SYSTEM);
    else     __hip_atomic_store(p, v, __ATOMIC_RELAXED, __HIP_MEMORY_SCOPE_AGENT);
}
__device__ __forceinline__ unsigned ld_sys32(const unsigned* p) {
    return __hip_atomic_load(p, __ATOMIC_RELAXED, __HIP_MEMORY_SCOPE_SYSTEM);
}

__device__ __forceinline__ float sigf(float x) {
    return __builtin_amdgcn_rcpf(1.0f + __expf(fminf(-x, 80.0f)));
}
__device__ __forceinline__ float tanhff(float x) {
    float e = __expf(fminf(2.0f * x, 80.0f));
    return (e - 1.0f) * __builtin_amdgcn_rcpf(e + 1.0f);
}

// h0 -> fragment-layout hfA: per bgrp 16KB; chunk ck (=j>>5) at ck*1024;
// slot = (qf*16 + b) ^ ck holds halfs e=0..7 = h[b][ck*32 + qf*8 + e].
__global__ void lstm_init(const float* __restrict__ h0, _Float16* __restrict__ hfA,
                          unsigned* __restrict__ ctrl) {
    int i = blockIdx.x * blockDim.x + threadIdx.x;  // 131072 = B*H
    int bb = i >> 9, j = i & 511;
    int bgrp = bb >> 4, b = bb & 15;
    int ck = j >> 5, jl = j & 31, qf = jl >> 3, e = jl & 7;
    int slot = (qf * 16 + b) ^ ck;
    hfA[bgrp * 8192 + ck * 512 + slot * 8 + e] = (_Float16)h0[i];
    if (i < 1152) ctrl[i] = 0u;  // flags[16*64] + regcnt[8] + regtotal
}

__global__ __launch_bounds__(256, 1) void lstm_persist(
    const float* __restrict__ obs, const float* __restrict__ act,
    const float* __restrict__ Wih, const float* __restrict__ Whh,
    const float* __restrict__ bih, const float* __restrict__ bhh,
    const float* __restrict__ Wout, const float* __restrict__ bout_p,
    const float* __restrict__ c0,
    _Float16* __restrict__ hfA, _Float16* __restrict__ hfB,
    unsigned* __restrict__ ctrl, float* __restrict__ out) {

    // LDS: [0,5K)=x buf0 (kc0-4), [5K,10K)=x buf1, [10K,26K)=h frags ck0-15.
    __shared__ __align__(16) char actT[26 * 1024];
    __shared__ float ypart[4];
    __shared__ float ytail[2];
    __shared__ int sh_role[3];  // bgrp, jg, sys

    const int tid = threadIdx.x;
    const int w = tid >> 6, ln = tid & 63;   // 4 waves
    const int lm = ln & 15, q = ln >> 4;     // MFMA lane decomposition

    unsigned* flags = ctrl;              // [16 bgrps][64] (one per producer wave)
    unsigned* regcnt = ctrl + 1024;      // [8]
    unsigned* regtotal = ctrl + 1032;    // [1]

    // ---- runtime XCD-aware role negotiation (one-time, verified R6) ----
    if (tid == 0) {
        int x = __builtin_amdgcn_s_getreg(20 | (31 << 11)) & 7;  // HW_REG_XCC_ID
        unsigned slot = atomicAdd(&regcnt[x], 1u);
        asm volatile("s_waitcnt vmcnt(0)" ::: "memory");
        atomicAdd(regtotal, 1u);
        while (ld_sys32(regtotal) < 256u) __builtin_amdgcn_s_sleep(8);
        unsigned cnt[8];
#pragma unroll
        for (int i = 0; i < 8; ++i) cnt[i] = ld_sys32(&regcnt[i]);
        int pure_base = 0, total_pure = 0, lbase = 0;
        for (int i = 0; i < 8; ++i) {
            if (i < x) { pure_base += cnt[i] >> 4; lbase += cnt[i] & 15; }
            total_pure += cnt[i] >> 4;
        }
        int px16 = (int)(cnt[x] >> 4) * 16;
        int bg, jv, sv;
        if ((int)slot < px16) {
            bg = pure_base + ((int)slot >> 4); jv = slot & 15; sv = 0;
        } else {
            int lr = lbase + ((int)slot - px16);
            bg = total_pure + (lr >> 4); jv = lr & 15; sv = 1;
        }
        sh_role[0] = bg; sh_role[1] = jv; sh_role[2] = sv;
    }
    __syncthreads();
    const int bgrp = sh_role[0], jg = sh_role[1];
    const bool sysS = sh_role[2] != 0;
    const int yb = bgrp * 16 + jg;
    unsigned* myflags = flags + bgrp * 64;

    // ---- persistent A fragments: wave w, tile ti -> j-local = w*8 + jj*2 + ti
    // (remap so lane (lm,q) holds gates of j-local = w*8 + q*2 + ti: the two
    //  epilogue halves (ti=0,1) form one fragment dword -> direct publish)
    v8h afrag[2][21];
    {
        const int jj = lm >> 2, gt = lm & 3;
#pragma unroll
        for (int ti = 0; ti < 2; ++ti) {
            const int grow = gt * kH + jg * 32 + w * 8 + jj * 2 + ti;
#pragma unroll
            for (int kc = 0; kc < 21; ++kc) {
                const int k0 = kc * 32 + q * 8;
                const float* src = (k0 < 160) ? (Wih + grow * 160 + k0)
                                              : (Whh + (size_t)grow * kH + (k0 - 160));
                float4 A = *(const float4*)src;
                float4 Bv = *(const float4*)(src + 4);
                v8h f;
                f[0] = (_Float16)A.x;  f[1] = (_Float16)A.y;
                f[2] = (_Float16)A.z;  f[3] = (_Float16)A.w;
                f[4] = (_Float16)Bv.x; f[5] = (_Float16)Bv.y;
                f[6] = (_Float16)Bv.z; f[7] = (_Float16)Bv.w;
                afrag[ti][kc] = f;
            }
        }
    }
    float biasv[2][4];
    float creg[2];
#pragma unroll
    for (int ti = 0; ti < 2; ++ti) {
        const int jloc = jg * 32 + w * 8 + q * 2 + ti;
#pragma unroll
        for (int g = 0; g < 4; ++g)
            biasv[ti][g] = bih[g * kH + jloc] + bhh[g * kH + jloc];
        creg[ti] = c0[(size_t)(bgrp * 16 + lm) * kH + jloc];
    }

    const float bout0 = bout_p[0];
    const float2 wout2 = *(const float2*)(Wout + 2 * tid);  // y: k = 2*tid
    float4 wout4 = make_float4(0.f, 0.f, 0.f, 0.f);
    if (tid < 128) wout4 = *(const float4*)(Wout + tid * 4);

    // x stager identity (threads 96..255; clear of wave0's poll)
    const int st = tid - 96, xb = st & 15, c10 = st >> 4;
    const bool isX = (tid >= 96);
    float4 xr[4];

    auto x_load = [&](int tt) {
        if (isX) {
            const size_t brow = (size_t)(bgrp * 16 + xb) * kT + tt;
            const float* p = (c10 < 8) ? (obs + brow * 128 + c10 * 16)
                                       : (act + brow * 32 + (c10 - 8) * 16);
            xr[0] = *(const float4*)(p);
            xr[1] = *(const float4*)(p + 4);
            xr[2] = *(const float4*)(p + 8);
            xr[3] = *(const float4*)(p + 12);
        }
    };
    auto x_write = [&](char* xbase) {
        if (isX) {
            const int kcx = c10 >> 1;
#pragma unroll
            for (int ii = 0; ii < 2; ++ii) {
                const int qx = (2 * c10 + ii) & 3;
                const int slot = (qx * 16 + xb) ^ kcx;
                float4 a = xr[2 * ii], b = xr[2 * ii + 1];
                v8h f;
                f[0] = (_Float16)a.x; f[1] = (_Float16)a.y;
                f[2] = (_Float16)a.z; f[3] = (_Float16)a.w;
                f[4] = (_Float16)b.x; f[5] = (_Float16)b.y;
                f[6] = (_Float16)b.z; f[7] = (_Float16)b.w;
                *(v8h*)(xbase + kcx * 1024 + slot * 16) = f;
            }
        }
    };

    // ---- initial x stage (t=0) into buffer 0 ----
    x_load(0);
    x_write(actT);
    __syncthreads();

    char* const hreg = actT + 10240;
    char* const hfAc = (char*)hfA;
    char* const hfBc = (char*)hfB;

#pragma unroll 1
    for (int t = 0; t < kT; ++t) {
        const char* hsrcB = ((t & 1) ? hfBc : hfAc) + (size_t)bgrp * 16384;
        char* hdstB = ((t & 1) ? hfAc : hfBc) + (size_t)bgrp * 16384;
        char* xcur = actT + ((t & 1) ? 5120 : 0);
        char* xnxt = actT + (((t + 1) & 1) ? 5120 : 0);

        // ---- 1. pre-issue next x loads (waves 1.5-3; wave0 goes to poll) ----
        if (t < kT - 1) x_load(t + 1);

        // ---- 2. wave0: poll the 64 per-wave flags ----
        if (t > 0 && tid < 64) {
            const unsigned tgt = (unsigned)t;
            const unsigned* fp = myflags + ln;
            while (true) {
                unsigned v = ld32sc(fp, sysS);
                if (__all((int)(v >= tgt))) break;
                __builtin_amdgcn_s_sleep(1);
            }
        }
        __syncthreads();  // P: h(t) published everywhere; LDS regions free

        // ---- 3. finalize y(t-2) from last iteration's partials ----
        if (t >= 2 && tid == 64)
            out[(size_t)yb * kT + (t - 2)] =
                bout0 + ypart[0] + ypart[1] + ypart[2] + ypart[3];

        // ---- 4. issue h-stage loads (verbatim 16KB fragment copy) ----
        ull u[8];
#pragma unroll
        for (int k = 0; k < 4; ++k) {
            const ull* sp = (const ull*)(hsrcB + k * 4096 + tid * 16);
            u[2 * k]     = ld64sc(sp, sysS);
            u[2 * k + 1] = ld64sc(sp + 1, sysS);
        }

        // ---- 5. x-part MFMA (kc 0..4) while h loads are in flight ----
        v4f a0 = {biasv[0][0], biasv[0][1], biasv[0][2], biasv[0][3]};
        v4f a1 = {biasv[1][0], biasv[1][1], biasv[1][2], biasv[1][3]};
#pragma unroll
        for (int kc = 0; kc < 5; ++kc) {
            v8h bfr = *(const v8h*)(xcur + kc * 1024 + (ln ^ kc) * 16);
            a0 = __builtin_amdgcn_mfma_f32_16x16x32_f16(afrag[0][kc], bfr, a0, 0, 0, 0);
            a1 = __builtin_amdgcn_mfma_f32_16x16x32_f16(afrag[1][kc], bfr, a1, 0, 0, 0);
        }

        // ---- 6. write staged h to LDS (linear b128); stage x(t+1) ----
#pragma unroll
        for (int k = 0; k < 4; ++k) {
            v2u val = {u[2 * k], u[2 * k + 1]};
            *(v2u*)(hreg + k * 4096 + tid * 16) = val;
        }
        x_write(xnxt);
        __syncthreads();  // S0: all activations staged

        // ---- 7. h-part MFMA (ck 0..15), split-K: 4 independent chains ----
        v4f b0 = {0.f, 0.f, 0.f, 0.f}, b1 = {0.f, 0.f, 0.f, 0.f};
#pragma unroll
        for (int ck = 0; ck < 8; ++ck) {
            v8h bfr = *(const v8h*)(hreg + ck * 1024 + (ln ^ ck) * 16);
            a0 = __builtin_amdgcn_mfma_f32_16x16x32_f16(afrag[0][5 + ck], bfr, a0, 0, 0, 0);
            a1 = __builtin_amdgcn_mfma_f32_16x16x32_f16(afrag[1][5 + ck], bfr, a1, 0, 0, 0);
        }
#pragma unroll
        for (int ck = 8; ck < 16; ++ck) {
            v8h bfr = *(const v8h*)(hreg + ck * 1024 + (ln ^ ck) * 16);
            b0 = __builtin_amdgcn_mfma_f32_16x16x32_f16(afrag[0][5 + ck], bfr, b0, 0, 0, 0);
            b1 = __builtin_amdgcn_mfma_f32_16x16x32_f16(afrag[1][5 + ck], bfr, b1, 0, 0, 0);
        }

        // ---- 8. epilogue + direct fragment-layout publish (per wave) ----
        // lane (lm,q) holds gates of j-local = w*8 + q*2 + ti, batch lm:
        // exactly dword q of slot (w*16 + (lm^jg)) in chunk jg.
        union { unsigned u32; _Float16 h2[2]; } pk;
#pragma unroll
        for (int ti = 0; ti < 2; ++ti) {
            v4f a = ti ? (a1 + b1) : (a0 + b0);
            float iv = sigf(a[0]), fv = sigf(a[1]);
            float gv = tanhff(a[2]), ov = sigf(a[3]);
            creg[ti] = fmaf(fv, creg[ti], iv * gv);
            pk.h2[ti] = (_Float16)(ov * tanhff(creg[ti]));
        }
        st32sc((unsigned*)(hdstB + jg * 1024 + (w * 16 + (lm ^ jg)) * 16 + q * 4),
               pk.u32, sysS);
        asm volatile("s_waitcnt vmcnt(0)" ::: "memory");
        if (ln == 0) st32sc(myflags + jg * 4 + w, (unsigned)(t + 1), sysS);

        // ---- 9. y(t-1) partials, off the critical path (next poll's shadow) ----
        if (t > 0) {
            const int k = 2 * tid;
            const int ck = k >> 5, qy = (k >> 3) & 3, e = k & 7;
            const int slot = (qy * 16 + jg) ^ ck;
            union { unsigned uu; _Float16 hh[2]; } cv;
            cv.uu = *(const unsigned*)(hreg + ck * 1024 + slot * 16 + e * 2);
            float p = (float)cv.hh[0] * wout2.x + (float)cv.hh[1] * wout2.y;
#pragma unroll
            for (int s = 32; s; s >>= 1) p += __shfl_xor(p, s);
            if (ln == 0) ypart[w] = p;
        }
    }

    // ---- tail: out[510] from pending partials; out[511] from h(T) in hfA ----
    if (tid < 64) {
        const unsigned* fp = myflags + ln;
        while (true) {
            unsigned v = ld32sc(fp, sysS);
            if (__all((int)(v >= (unsigned)kT))) break;
            __builtin_amdgcn_s_sleep(1);
        }
    }
    __syncthreads();
    if (tid == 64)
        out[(size_t)yb * kT + (kT - 2)] =
            bout0 + ypart[0] + ypart[1] + ypart[2] + ypart[3];
    if (tid < 128) {
        const int j0 = tid * 4;
        const int ck = j0 >> 5, qf = (j0 >> 3) & 3, e0 = j0 & 7;
        const int slot = (qf * 16 + jg) ^ ck;
        union { ull uu; _Float16 h4[4]; } cv;
        cv.uu = ld64sc((const ull*)(hfAc + (size_t)bgrp * 16384 + ck * 1024 +
                                    slot * 16 + e0 * 2), sysS);
        float p = (float)cv.h4[0] * wout4.x + (float)cv.h4[1] * wout4.y +
                  (float)cv.h4[2] * wout4.z + (float)cv.h4[3] * wout4.w;
#pragma unroll
        for (int s = 32; s; s >>= 1) p += __shfl_xor(p, s);
        if (ln == 0) ytail[w] = p;
    }
    __syncthreads();
    if (tid == 0) out[(size_t)yb * kT + (kT - 1)] = ytail[0] + ytail[1] + bout0;
}

}  // namespace

extern "C" void kernel_launch(void* const* d_in, const int* in_sizes, int n_in,
                              void* d_out, int out_size, void* d_ws, size_t ws_size,
                              hipStream_t stream) {
    const float* obs  = (const float*)d_in[0];
    const float* act  = (const float*)d_in[1];
    const float* Wih  = (const float*)d_in[2];
    const float* Whh  = (const float*)d_in[3];
    const float* bih  = (const float*)d_in[4];
    const float* bhh  = (const float*)d_in[5];
    const float* Wout = (const float*)d_in[6];
    const float* bout = (const float*)d_in[7];
    const float* h0   = (const float*)d_in[8];
    const float* c0   = (const float*)d_in[9];
    float* out = (float*)d_out;

    char* ws = (char*)d_ws;
    _Float16* hfA = (_Float16*)ws;                 // frag-layout h, 256 KB
    _Float16* hfB = (_Float16*)(ws + 262144);      // frag-layout h, 256 KB
    unsigned* ctrl = (unsigned*)(ws + 524288);     // flags[1024] + regcnt[8] + regtotal

    lstm_init<<<512, 256, 0, stream>>>(h0, hfA, ctrl);
    lstm_persist<<<256, 256, 0, stream>>>(obs, act, Wih, Whh, bih, bhh, Wout, bout,
                                          c0, hfA, hfB, ctrl, out);
}